// Round 3
// baseline (2817.833 us; speedup 1.0000x reference)
//
#include <hip/hip_runtime.h>
#include <math.h>

#define NB 64
#define NT 2048
#define NI 64
#define NS 128
#define NO 64

typedef float4 f4;

// ---------- fast cross-lane helpers (VALU DPP, not DS pipe) ----------
template<int CTRL>
__device__ __forceinline__ float dpp_add(float v) {
    int t = __builtin_amdgcn_update_dpp(0, __float_as_int(v), CTRL, 0xF, 0xF, true);
    return v + __int_as_float(t);
}
// combine across lane^1 (quad_perm [1,0,3,2]) and lane^2 (quad_perm [2,3,0,1])
__device__ __forceinline__ float qxor1(float v) { return dpp_add<0xB1>(v); }
__device__ __forceinline__ float qxor2(float v) { return dpp_add<0x4E>(v); }
// full wave-64 sum; result valid in lane 63 only (row_shr cascade + bcast15/31)
__device__ __forceinline__ float wave_sum63(float v) {
    v = dpp_add<0x111>(v);
    v = dpp_add<0x112>(v);
    v = dpp_add<0x114>(v);
    v = dpp_add<0x118>(v);
    v = dpp_add<0x142>(v);
    v = dpp_add<0x143>(v);
    return v;
}

__device__ __forceinline__ float sigmoidf_fast(float z) {
    float e = __builtin_amdgcn_exp2f(z * -1.442695041f);
    return __builtin_amdgcn_rcpf(1.0f + e);
}

__device__ __forceinline__ void bar_lds() {
    asm volatile("s_waitcnt lgkmcnt(0)" ::: "memory");
    __builtin_amdgcn_s_barrier();
}

// =====================================================================
// K1: sequential scan. One block (512 thr, 8 waves) per batch.
// thread: q = tid&3 (K-quarter), r = tid>>2 (state row 0..127).
// Weights per thread: A-slice 32 + B-slice 16 + W-slice 16 = 64 regs.
// State kept as RAW pre-LN m; LN folded into A via gamma/beta.
// Single barrier per step; parity double-buffered LDS.
// =====================================================================
__global__ __launch_bounds__(512, 2) void scan_kernel(
    const float* __restrict__ x,     // [NB][NT][NI]
    const float* __restrict__ A,     // [NS][NS]
    const float* __restrict__ Bm,    // [NS][NI]
    const float* __restrict__ Wsel,  // [NS][NI]
    const float* __restrict__ bsel,  // [NS]
    const float* __restrict__ gamma, // [NS]
    const float* __restrict__ beta,  // [NS]
    float* __restrict__ H,           // ws [NB][NT][NS]  raw m
    float* __restrict__ musig)       // ws [NB][NT] float2 (mu, rstd)
{
    const int b    = blockIdx.x;
    const int tid  = threadIdx.x;
    const int q    = tid & 3;
    const int r    = tid >> 2;      // 0..127
    const int lane = tid & 63;
    const int wave = tid >> 6;      // 0..7

    // padded: quarter qq lives at float offset qq*36 (conflict-free b128 reads)
    __shared__ __align__(16) float hbuf[2][148];
    __shared__ __align__(16) float red[2][16];   // [par][ s(0..7) | s2(8..15) ]

    // ---- weights: A gamma-folded + fold scalars ----
    float a_w[32];
    float sAg = 0.f, aB = 0.f;
    {
        const f4* ga = (const f4*)(gamma + q * 32);
        const f4* bb = (const f4*)(beta  + q * 32);
        const f4* Ap = (const f4*)(A + (size_t)r * NS + q * 32);
        #pragma unroll
        for (int j = 0; j < 8; ++j) {
            f4 g = ga[j], be_ = bb[j], v = Ap[j];
            float f0 = v.x * g.x, f1 = v.y * g.y, f2 = v.z * g.z, f3 = v.w * g.w;
            a_w[4*j+0] = f0; a_w[4*j+1] = f1; a_w[4*j+2] = f2; a_w[4*j+3] = f3;
            sAg += (f0 + f1) + (f2 + f3);
            aB = fmaf(v.x, be_.x, aB); aB = fmaf(v.y, be_.y, aB);
            aB = fmaf(v.z, be_.z, aB); aB = fmaf(v.w, be_.w, aB);
        }
        sAg = qxor2(qxor1(sAg));
        aB  = qxor2(qxor1(aB));
    }
    float b_w[16], w_w[16];
    {
        const f4* Bp = (const f4*)(Bm   + (size_t)r * NI + q * 16);
        const f4* Wp = (const f4*)(Wsel + (size_t)r * NI + q * 16);
        #pragma unroll
        for (int j = 0; j < 4; ++j) {
            f4 v;
            v = Bp[j]; b_w[4*j+0]=v.x; b_w[4*j+1]=v.y; b_w[4*j+2]=v.z; b_w[4*j+3]=v.w;
            v = Wp[j]; w_w[4*j+0]=v.x; w_w[4*j+1]=v.y; w_w[4*j+2]=v.z; w_w[4*j+3]=v.w;
        }
    }
    const float bs = bsel[r];
    const float gm = gamma[r];
    const float bt = beta[r];

    const float* xq = x + ((size_t)b * NT) * NI + q * 16;
    f4 xb0[4], xb1[4];
    #pragma unroll
    for (int j = 0; j < 4; ++j) xb0[j] = ((const f4*)xq)[j];        // x_0
    #pragma unroll
    for (int j = 0; j < 4; ++j) xb1[j] = ((const f4*)(xq + NI))[j]; // x_1

    // pending x-projections for one timestep
    float zp, dBp;
    auto xdots = [&](const f4 (&xv)[4]) {
        float p = 0.f, pw = 0.f;
        #pragma unroll
        for (int j = 0; j < 4; ++j) {
            f4 v = xv[j];
            p  = fmaf(b_w[4*j+0], v.x, p);  p  = fmaf(b_w[4*j+1], v.y, p);
            p  = fmaf(b_w[4*j+2], v.z, p);  p  = fmaf(b_w[4*j+3], v.w, p);
            pw = fmaf(w_w[4*j+0], v.x, pw); pw = fmaf(w_w[4*j+1], v.y, pw);
            pw = fmaf(w_w[4*j+2], v.z, pw); pw = fmaf(w_w[4*j+3], v.w, pw);
        }
        dBp = qxor2(qxor1(p));
        zp  = qxor2(qxor1(pw)) + bs;
    };

    float*  Hb   = H + ((size_t)b * NT) * NS;
    float2* musb = (float2*)musig + (size_t)b * NT;

    // ---- peel t = 0 : h_prev = 0, dA = 0 ----
    float mp;   // raw m for own row (prev step)
    xdots(xb0);
    {
        float g = sigmoidf_fast(zp);
        mp = g * dBp;
        if (q == 0) {
            hbuf[0][((r >> 5) * 36) + (r & 31)] = mp;
            Hb[r] = mp;
        }
        float s  = wave_sum63(mp);
        float s2 = wave_sum63(mp * mp);
        if (lane == 63) { red[0][wave] = s; red[0][8 + wave] = s2; }
    }
    xdots(xb1);  // pending z/dB for t=1
    #pragma unroll
    for (int j = 0; j < 4; ++j) xb0[j] = ((const f4*)(xq + 2 * NI))[j]; // x_2
    bar_lds();

    // ---- main step body ----
    auto body = [&](int t, int parIn, int parOut, f4 (&xUse)[4], f4 (&xPre)[4]) {
        // 1. prefetch x_{t+2}
        if (t + 2 < NT) {
            const f4* px = (const f4*)(xq + (size_t)(t + 2) * NI);
            #pragma unroll
            for (int j = 0; j < 4; ++j) xPre[j] = px[j];
        }
        // 2. stats of m_{t-1} (broadcast LDS reads)
        f4 sa = *((const f4*)&red[parIn][0]);
        f4 sb = *((const f4*)&red[parIn][4]);
        f4 sc = *((const f4*)&red[parIn][8]);
        f4 sd = *((const f4*)&red[parIn][12]);
        float S  = ((sa.x + sa.y) + (sa.z + sa.w)) + ((sb.x + sb.y) + (sb.z + sb.w));
        float S2 = ((sc.x + sc.y) + (sc.z + sc.w)) + ((sd.x + sd.y) + (sd.z + sd.w));
        float mu   = S * (1.0f / 512.0f);              // 4x dup, 128 rows
        float var  = fmaf(S2, 1.0f / 512.0f, -mu * mu);
        float rstd = 1.0f / sqrtf(var + 1e-5f);
        // 3. A-dot on raw m_{t-1} (gamma-folded)
        const f4* hp = (const f4*)&hbuf[parIn][q * 36];
        float d0 = 0.f, d1 = 0.f, d2 = 0.f, d3 = 0.f;
        #pragma unroll
        for (int j = 0; j < 8; ++j) {
            f4 v = hp[j];
            d0 = fmaf(a_w[4*j+0], v.x, d0);
            d1 = fmaf(a_w[4*j+1], v.y, d1);
            d2 = fmaf(a_w[4*j+2], v.z, d2);
            d3 = fmaf(a_w[4*j+3], v.w, d3);
        }
        float dAm = qxor2(qxor1((d0 + d1) + (d2 + d3)));
        float dA  = fmaf(rstd, fmaf(-mu, sAg, dAm), aB);
        // 4. own-row prev LN value
        float hpl = fmaf((mp - mu) * rstd, gm, bt);
        // 5. gate / mix -> m_t
        float g  = sigmoidf_fast(zp);
        float hn = dA + dBp;
        float m  = fmaf(g, hn - hpl, hpl);
        // 6. publish state (LDS + fire-and-forget global)
        if (q == 0) {
            hbuf[parOut][((r >> 5) * 36) + (r & 31)] = m;
            Hb[(size_t)t * NS + r] = m;
        }
        // 7. wave stats reduce of m_t
        float s  = wave_sum63(m);
        float s2 = wave_sum63(m * m);
        if (lane == 63) { red[parOut][wave] = s; red[parOut][8 + wave] = s2; }
        // 8. musig for t-1
        if (tid == 0) musb[t - 1] = make_float2(mu, rstd);
        mp = m;
        // 9. x-projections for t+1
        if (t + 1 < NT) xdots(xUse);
        // 10. single barrier
        bar_lds();
    };

    for (int t = 1; t + 1 < NT; t += 2) {
        body(t,     0, 1, xb0, xb1);
        body(t + 1, 1, 0, xb1, xb0);
    }
    body(NT - 1, 0, 1, xb0, xb1);

    // epilogue: stats of m_{NT-1}
    {
        f4 sa = *((const f4*)&red[1][0]);
        f4 sb = *((const f4*)&red[1][4]);
        f4 sc = *((const f4*)&red[1][8]);
        f4 sd = *((const f4*)&red[1][12]);
        float S  = ((sa.x + sa.y) + (sa.z + sa.w)) + ((sb.x + sb.y) + (sb.z + sb.w));
        float S2 = ((sc.x + sc.y) + (sc.z + sc.w)) + ((sd.x + sd.y) + (sd.z + sd.w));
        float mu   = S * (1.0f / 512.0f);
        float var  = fmaf(S2, 1.0f / 512.0f, -mu * mu);
        float rstd = 1.0f / sqrtf(var + 1e-5f);
        if (tid == 0) musb[NT - 1] = make_float2(mu, rstd);
    }
}

// =====================================================================
// K2: y + statistics. grid = NB x 32 chunks of 64 t, 512 threads.
// Thread: o = tid&63, kh = (tid>>6)&1 (K-half), tg = tid>>7 (t-group).
// Phase 1: per-(kh,tg) wave writes y-partials for 16 t into LDS.
// Phase 2: wave sub reduces 8 t: norms/diffs via DPP, scalars via LDS.
// y = rstd*(dot(Cg,m) - mu*sCg) + dot(C,beta) + dot(D,x)
// =====================================================================
#define CHUNKS 32
#define TCH (NT / CHUNKS)   // 64

__global__ __launch_bounds__(512, 2) void y_stats_kernel(
    const float* __restrict__ H,
    const float* __restrict__ x,
    const float* __restrict__ Cm,
    const float* __restrict__ Dm,
    const float* __restrict__ gamma,
    const float* __restrict__ beta,
    const float* __restrict__ musig,
    float* __restrict__ SY,
    float* __restrict__ SYY,
    float* __restrict__ meanx,     // raw sums (divided in K3)
    float* __restrict__ nsum,
    float* __restrict__ dsum,
    float* __restrict__ outFinal)
{
    const int b     = blockIdx.x >> 5;
    const int chunk = blockIdx.x & 31;
    const int tid   = threadIdx.x;
    const int o     = tid & 63;
    const int sub   = tid >> 6;      // 0..7
    const int kh    = sub & 1;
    const int tg    = sub >> 1;      // 0..3
    const int lane  = tid & 63;

    __shared__ float pbuf[TCH + 1][2 * NO];   // [t-t0+1][kh*64+o]  33.3 KB
    __shared__ float nd[2];                   // block accum: {na, da}

    // ---- C half (gamma folded) + D half in regs ----
    float c_w[64]; float sCg = 0.f, cB = 0.f;
    {
        const f4* cp = (const f4*)(Cm + (size_t)o * NS + kh * 64);
        const f4* gp = (const f4*)(gamma + kh * 64);
        const f4* bp = (const f4*)(beta  + kh * 64);
        #pragma unroll
        for (int j = 0; j < 16; ++j) {
            f4 v = cp[j], g = gp[j], be = bp[j];
            float f0 = v.x * g.x, f1 = v.y * g.y, f2 = v.z * g.z, f3 = v.w * g.w;
            c_w[4*j+0] = f0; c_w[4*j+1] = f1; c_w[4*j+2] = f2; c_w[4*j+3] = f3;
            sCg += (f0 + f1) + (f2 + f3);
            cB = fmaf(v.x, be.x, cB); cB = fmaf(v.y, be.y, cB);
            cB = fmaf(v.z, be.z, cB); cB = fmaf(v.w, be.w, cB);
        }
    }
    float d_w[32];
    {
        const f4* dp = (const f4*)(Dm + (size_t)o * NI + kh * 32);
        #pragma unroll
        for (int j = 0; j < 8; ++j) {
            f4 v = dp[j];
            d_w[4*j+0] = v.x; d_w[4*j+1] = v.y; d_w[4*j+2] = v.z; d_w[4*j+3] = v.w;
        }
    }

    const float*  Hb  = H + ((size_t)b * NT) * NS;
    const float*  xb  = x + ((size_t)b * NT) * NI;
    const float2* msb = (const float2*)musig + (size_t)b * NT;
    const int t0 = chunk * TCH;

    if (tid < 2) nd[tid] = 0.f;

    // ---- meanx partials: 4 waves x 16 t each, column o ----
    if (sub < 4) {
        float s = 0.f;
        const float* xk = xb + o;
        #pragma unroll 4
        for (int i = 0; i < 16; ++i) s += xk[(size_t)(t0 + sub * 16 + i) * NI];
        atomicAdd(&meanx[b * NI + o], s);
    }

    // ---- phase 1: y-partials into LDS (tg==0 also does the t0-1 halo) ----
    {
        const int i_start = (tg == 0 && t0 > 0) ? -1 : 0;
        for (int i = i_start; i < 16; ++i) {
            const int t = t0 + tg * 16 + i;
            float2 ms = msb[t];
            const f4* hp = (const f4*)(Hb + (size_t)t * NS + kh * 64);
            const f4* xp = (const f4*)(xb + (size_t)t * NI + kh * 32);
            float y0 = 0.f, y1 = 0.f, y2 = 0.f, y3 = 0.f;
            #pragma unroll
            for (int j = 0; j < 16; ++j) {
                f4 hv = hp[j];
                y0 = fmaf(c_w[4*j+0], hv.x, y0);
                y1 = fmaf(c_w[4*j+1], hv.y, y1);
                y2 = fmaf(c_w[4*j+2], hv.z, y2);
                y3 = fmaf(c_w[4*j+3], hv.w, y3);
            }
            float hdot = (y0 + y1) + (y2 + y3);
            float x0 = 0.f, x1 = 0.f, x2 = 0.f, x3 = 0.f;
            #pragma unroll
            for (int j = 0; j < 8; ++j) {
                f4 xv = xp[j];
                x0 = fmaf(d_w[4*j+0], xv.x, x0);
                x1 = fmaf(d_w[4*j+1], xv.y, x1);
                x2 = fmaf(d_w[4*j+2], xv.z, x2);
                x3 = fmaf(d_w[4*j+3], xv.w, x3);
            }
            float xdot = (x0 + x1) + (x2 + x3);
            float part = fmaf(ms.y, fmaf(-ms.x, sCg, hdot), 0.5f * cB + xdot);
            // cB split evenly across the two kh halves? No: cB is computed
            // per-half already (beta slice kh*64..) -> full cB = cB0 + cB1.
            part = fmaf(ms.y, 0.f, part); // no-op keep
            pbuf[tg * 16 + i + 1][kh * 64 + o] = fmaf(ms.y, fmaf(-ms.x, sCg, hdot), cB + xdot) - part + part;
            pbuf[tg * 16 + i + 1][kh * 64 + o] = fmaf(ms.y, fmaf(-ms.x, sCg, hdot), cB + xdot);
        }
    }
    __syncthreads();

    // ---- phase 2: wave sub reduces t = t0 + sub*8 .. +8 ----
    {
        const int tt0 = sub * 8;
        float yprev = pbuf[tt0][o] + pbuf[tt0][64 + o];   // halo (garbage iff t==0, guarded)
        float sy = 0.f, syy = 0.f, na = 0.f, da = 0.f;
        #pragma unroll
        for (int ii = 0; ii < 8; ++ii) {
            const int row = tt0 + ii + 1;
            float y = pbuf[row][o] + pbuf[row][64 + o];
            sy  += y;
            syy += y * y;
            float n2 = wave_sum63(y * y);
            na += sqrtf(n2);
            if (t0 + tt0 + ii > 0) {
                float df = y - yprev;
                float d2 = wave_sum63(df * df);
                da += sqrtf(d2);
            }
            yprev = y;
            if (chunk == 31 && sub == 7 && ii == 7)
                outFinal[b * NO + o] = y;
        }
        atomicAdd(&SY[b * NO + o], sy);
        atomicAdd(&SYY[b * NO + o], syy);
        if (lane == 63) {
            atomicAdd(&nd[0], na);
            atomicAdd(&nd[1], da);
        }
    }
    __syncthreads();
    if (tid == 0) { atomicAdd(nsum, nd[0]); atomicAdd(dsum, nd[1]); }
}

// =====================================================================
// K3: finalize scalars
// =====================================================================
__global__ __launch_bounds__(256) void finalize_kernel(
    const float* __restrict__ Wsel,
    const float* __restrict__ bsel,
    const float* __restrict__ meanx,   // raw sums
    const float* __restrict__ SY,
    const float* __restrict__ SYY,
    const float* __restrict__ nsum,
    const float* __restrict__ dsum,
    float* __restrict__ out)
{
    const int tid  = threadIdx.x;
    const int wave = tid >> 6;
    const int lane = tid & 63;
    __shared__ float rs[8];

    float accsel = 0.f;
    for (int idx = tid; idx < NB * NS; idx += 256) {
        int bb = idx >> 7;
        int s  = idx & 127;
        const float* mp = meanx + bb * NI;
        const float* wp = Wsel  + (size_t)s * NI;
        float dot = 0.f;
        #pragma unroll 8
        for (int k = 0; k < NI; ++k) dot = fmaf(mp[k], wp[k], dot);
        float z = fmaf(dot, 1.0f / NT, bsel[s]);
        accsel += 1.0f / (1.0f + expf(-z));
    }
    float accss = 0.f;
    for (int idx = tid; idx < NB * NO; idx += 256) {
        float s1 = SY[idx], s2 = SYY[idx];
        float var = (s2 - s1 * s1 * (1.0f / NT)) * (1.0f / (NT - 1));
        accss += sqrtf(fmaxf(var, 0.0f));
    }
    #pragma unroll
    for (int d = 1; d < 64; d <<= 1) {
        accsel += __shfl_xor(accsel, d);
        accss  += __shfl_xor(accss, d);
    }
    if (lane == 0) { rs[wave] = accsel; rs[4 + wave] = accss; }
    __syncthreads();
    if (tid == 0) {
        float sel = (rs[0] + rs[1] + rs[2] + rs[3]) / (float)(NB * NS);
        float ss  = (rs[4] + rs[5] + rs[6] + rs[7]) / (float)(NB * NO);
        float tc  = 1.0f / (1.0f + dsum[0] / (float)(NB * (NT - 1)));
        float sm  = nsum[0] / (float)(NB * NT);
        out[4096] = tc;
        out[4097] = sm;
        out[4098] = sel;
        out[4099] = ss;
    }
}

extern "C" void kernel_launch(void* const* d_in, const int* in_sizes, int n_in,
                              void* d_out, int out_size, void* d_ws, size_t ws_size,
                              hipStream_t stream)
{
    (void)in_sizes; (void)n_in; (void)out_size; (void)ws_size;
    const float* x     = (const float*)d_in[0];
    const float* A     = (const float*)d_in[1];
    const float* Bm    = (const float*)d_in[2];
    const float* Cm    = (const float*)d_in[3];
    const float* Dm    = (const float*)d_in[4];
    const float* Wsel  = (const float*)d_in[5];
    const float* bsel  = (const float*)d_in[6];
    const float* gamma = (const float*)d_in[7];
    const float* beta  = (const float*)d_in[8];
    float* out = (float*)d_out;

    char* ws = (char*)d_ws;
    size_t off = 0;
    float* H     = (float*)(ws + off); off += (size_t)NB * NT * NS * sizeof(float); // 64 MB
    float* musig = (float*)(ws + off); off += (size_t)NB * NT * 2 * sizeof(float);  // 1 MB
    char*  zbase = ws + off;
    float* SY    = (float*)(ws + off); off += NB * NO * sizeof(float);
    float* SYY   = (float*)(ws + off); off += NB * NO * sizeof(float);
    float* meanx = (float*)(ws + off); off += NB * NI * sizeof(float);
    float* nsum  = (float*)(ws + off); off += sizeof(float);
    float* dsum  = (float*)(ws + off); off += sizeof(float);
    size_t zbytes = (size_t)((char*)(dsum + 1) - zbase);

    hipMemsetAsync(zbase, 0, zbytes, stream);
    scan_kernel<<<NB, 512, 0, stream>>>(x, A, Bm, Wsel, bsel, gamma, beta, H, musig);
    y_stats_kernel<<<NB * CHUNKS, 512, 0, stream>>>(H, x, Cm, Dm, gamma, beta, musig,
                                                    SY, SYY, meanx, nsum, dsum, out);
    finalize_kernel<<<1, 256, 0, stream>>>(Wsel, bsel, meanx, SY, SYY, nsum, dsum, out);
}

// Round 6
// 1942.848 us; speedup vs baseline: 1.4504x; 1.4504x over previous
//
#include <hip/hip_runtime.h>
#include <math.h>

#define NB 64
#define NT 2048
#define NI 64
#define NS 128
#define NO 64

typedef float4 f4;

// Pin a float4's lanes into VGPRs: asm redefines the values, so the compiler
// can neither rematerialize them from memory nor sink the producing loads.
#define PIN4(v) asm("" : "+v"((v).x), "+v"((v).y), "+v"((v).z), "+v"((v).w))

// NOTE: macro params must NOT be named x/y/z/w/v-members — preprocessor
// substitutes after '.' too (round-4 compile failure).
#define FMA4(a0,a1,a2,a3,W_,V_) \
    a0 = fmaf((W_).x, (V_).x, a0); a1 = fmaf((W_).y, (V_).y, a1); \
    a2 = fmaf((W_).z, (V_).z, a2); a3 = fmaf((W_).w, (V_).w, a3)

// ---------- fast cross-lane helpers (VALU DPP, not DS pipe) ----------
template<int CTRL>
__device__ __forceinline__ float dpp_add(float v) {
    int t = __builtin_amdgcn_update_dpp(0, __float_as_int(v), CTRL, 0xF, 0xF, true);
    return v + __int_as_float(t);
}
__device__ __forceinline__ float qxor1(float v) { return dpp_add<0xB1>(v); }  // lane^1
__device__ __forceinline__ float qxor2(float v) { return dpp_add<0x4E>(v); }  // lane^2
// full wave-64 sum; valid in lane 63 (row_shr cascade + row_bcast15/31)
__device__ __forceinline__ float wave_sum63(float v) {
    v = dpp_add<0x111>(v); v = dpp_add<0x112>(v); v = dpp_add<0x114>(v);
    v = dpp_add<0x118>(v); v = dpp_add<0x142>(v); v = dpp_add<0x143>(v);
    return v;
}

__device__ __forceinline__ float sigmoidf_fast(float z) {
    float e = __builtin_amdgcn_exp2f(z * -1.442695041f);
    return __builtin_amdgcn_rcpf(1.0f + e);
}

// Barrier that waits only LDS (keeps fire-and-forget global stores + DMA in flight)
__device__ __forceinline__ void bar_lds() {
    asm volatile("s_waitcnt lgkmcnt(0)" ::: "memory");
    __builtin_amdgcn_s_barrier();
    asm volatile("" ::: "memory");
}

// async global->LDS DMA, 16B per lane, dst = uniform base + lane*16
__device__ __forceinline__ void stage16(const float* g, float* l) {
    __builtin_amdgcn_global_load_lds(
        (const __attribute__((address_space(1))) void*)g,
        (__attribute__((address_space(3))) void*)l, 16, 0, 0);
}

// =====================================================================
// K1: sequential scan. One block (512 thr, 8 waves) per batch.
// thread: q = tid&3 (K-quarter), r = tid>>2 (state row 0..127).
// Weights pinned in VGPRs; x staged via global_load_lds (32-step chunks,
// double-buffered); state kept RAW pre-LN, LN folded into A.
// =====================================================================
__global__ __launch_bounds__(512, 2) void scan_kernel(
    const float* __restrict__ x,     // [NB][NT][NI]
    const float* __restrict__ A,     // [NS][NS]
    const float* __restrict__ Bm,    // [NS][NI]
    const float* __restrict__ Wsel,  // [NS][NI]
    const float* __restrict__ bsel,  // [NS]
    const float* __restrict__ gamma, // [NS]
    const float* __restrict__ beta,  // [NS]
    float* __restrict__ H,           // ws [NB][NT][NS]  raw m
    float* __restrict__ musig)       // ws [NB][NT] float2 (mu, rstd)
{
    const int b    = blockIdx.x;
    const int tid  = threadIdx.x;
    const int q    = tid & 3;
    const int r    = tid >> 2;      // 0..127
    const int lane = tid & 63;
    const int wave = tid >> 6;      // 0..7

    __shared__ __align__(16) float hbuf[2][148];   // quarter qq at offset qq*36
    __shared__ __align__(16) float red[2][16];     // [par][ s(0..7) | s2(8..15) ]
    __shared__ __align__(16) float xlds[2][32][64];// x chunks, 16 KB

    // ---- weights: A gamma-folded, named f4s, pinned ----
    f4 Aw0, Aw1, Aw2, Aw3, Aw4, Aw5, Aw6, Aw7;
    float sAg = 0.f, aB = 0.f;
    {
        const f4* ga = (const f4*)(gamma + q * 32);
        const f4* bb = (const f4*)(beta  + q * 32);
        const f4* Ap = (const f4*)(A + (size_t)r * NS + q * 32);
        f4 g, be_, v;
#define LOADA(J, AW) \
        g = ga[J]; be_ = bb[J]; v = Ap[J]; \
        AW.x = v.x * g.x; AW.y = v.y * g.y; AW.z = v.z * g.z; AW.w = v.w * g.w; \
        sAg += (AW.x + AW.y) + (AW.z + AW.w); \
        aB = fmaf(v.x, be_.x, aB); aB = fmaf(v.y, be_.y, aB); \
        aB = fmaf(v.z, be_.z, aB); aB = fmaf(v.w, be_.w, aB);
        LOADA(0, Aw0) LOADA(1, Aw1) LOADA(2, Aw2) LOADA(3, Aw3)
        LOADA(4, Aw4) LOADA(5, Aw5) LOADA(6, Aw6) LOADA(7, Aw7)
#undef LOADA
        sAg = qxor2(qxor1(sAg));
        aB  = qxor2(qxor1(aB));
    }
    f4 Bw0, Bw1, Bw2, Bw3, Ww0, Ww1, Ww2, Ww3;
    {
        const f4* Bp = (const f4*)(Bm   + (size_t)r * NI + q * 16);
        const f4* Wp = (const f4*)(Wsel + (size_t)r * NI + q * 16);
        Bw0 = Bp[0]; Bw1 = Bp[1]; Bw2 = Bp[2]; Bw3 = Bp[3];
        Ww0 = Wp[0]; Ww1 = Wp[1]; Ww2 = Wp[2]; Ww3 = Wp[3];
    }
    float bs = bsel[r], gm = gamma[r], bt = beta[r];

    PIN4(Aw0); PIN4(Aw1); PIN4(Aw2); PIN4(Aw3);
    PIN4(Aw4); PIN4(Aw5); PIN4(Aw6); PIN4(Aw7);
    PIN4(Bw0); PIN4(Bw1); PIN4(Bw2); PIN4(Bw3);
    PIN4(Ww0); PIN4(Ww1); PIN4(Ww2); PIN4(Ww3);
    asm("" : "+v"(sAg), "+v"(aB), "+v"(bs), "+v"(gm), "+v"(bt));

    // ---- stage x chunks 0,1 ----
    const float* xstage = x + (size_t)b * NT * NI + wave * 256 + lane * 4;
    stage16(xstage,        &xlds[0][wave * 4][0]);
    stage16(xstage + 2048, &xlds[1][wave * 4][0]);
    asm volatile("s_waitcnt vmcnt(0)" ::: "memory");
    __syncthreads();

    float zp, dBp;   // pending x-projections for one timestep
    auto xdots = [&](int t) {
        const f4* xp = (const f4*)&xlds[(t >> 5) & 1][t & 31][q * 16];
        f4 v0 = xp[0], v1 = xp[1], v2 = xp[2], v3 = xp[3];
        float p0 = 0.f, p1 = 0.f, p2 = 0.f, p3 = 0.f;
        float w0 = 0.f, w1 = 0.f, w2 = 0.f, w3 = 0.f;
        FMA4(p0, p1, p2, p3, Bw0, v0); FMA4(p0, p1, p2, p3, Bw1, v1);
        FMA4(p0, p1, p2, p3, Bw2, v2); FMA4(p0, p1, p2, p3, Bw3, v3);
        FMA4(w0, w1, w2, w3, Ww0, v0); FMA4(w0, w1, w2, w3, Ww1, v1);
        FMA4(w0, w1, w2, w3, Ww2, v2); FMA4(w0, w1, w2, w3, Ww3, v3);
        dBp = qxor2(qxor1((p0 + p1) + (p2 + p3)));
        zp  = qxor2(qxor1((w0 + w1) + (w2 + w3))) + bs;
    };

    float*  Hb   = H + ((size_t)b * NT) * NS;
    float2* musb = (float2*)musig + (size_t)b * NT;

    // ---- peel t = 0 : h_prev = 0, dA = 0 ----
    float mp;
    xdots(0);
    {
        float g = sigmoidf_fast(zp);
        mp = g * dBp;
        if (q == 0) {
            hbuf[0][((r >> 5) * 36) + (r & 31)] = mp;
            Hb[r] = mp;
        }
        float s  = wave_sum63(mp);
        float s2 = wave_sum63(mp * mp);
        if (lane == 63) { red[0][wave] = s; red[0][8 + wave] = s2; }
    }
    xdots(1);
    bar_lds();

    auto body = [&](int t, int parIn, int parOut) {
        // stats of m_{t-1}
        const f4* rp = (const f4*)&red[parIn][0];
        f4 sa = rp[0], sb = rp[1], sc = rp[2], sd = rp[3];
        float S  = ((sa.x + sa.y) + (sa.z + sa.w)) + ((sb.x + sb.y) + (sb.z + sb.w));
        float S2 = ((sc.x + sc.y) + (sc.z + sc.w)) + ((sd.x + sd.y) + (sd.z + sd.w));
        float mu   = S * (1.0f / 512.0f);              // 4x dup, 128 rows
        float var  = fmaf(S2, 1.0f / 512.0f, -mu * mu);
        float rstd = 1.0f / sqrtf(var + 1e-5f);
        // A-dot on raw m_{t-1} (gamma-folded)
        const f4* hp = (const f4*)&hbuf[parIn][q * 36];
        f4 h0 = hp[0], h1 = hp[1], h2 = hp[2], h3 = hp[3];
        f4 h4 = hp[4], h5 = hp[5], h6 = hp[6], h7 = hp[7];
        float d0 = 0.f, d1 = 0.f, d2 = 0.f, d3 = 0.f;
        FMA4(d0, d1, d2, d3, Aw0, h0); FMA4(d0, d1, d2, d3, Aw1, h1);
        FMA4(d0, d1, d2, d3, Aw2, h2); FMA4(d0, d1, d2, d3, Aw3, h3);
        FMA4(d0, d1, d2, d3, Aw4, h4); FMA4(d0, d1, d2, d3, Aw5, h5);
        FMA4(d0, d1, d2, d3, Aw6, h6); FMA4(d0, d1, d2, d3, Aw7, h7);
        float dAm = qxor2(qxor1((d0 + d1) + (d2 + d3)));
        float dA  = fmaf(rstd, fmaf(-mu, sAg, dAm), aB);
        // own-row prev LN value
        float hpl = fmaf((mp - mu) * rstd, gm, bt);
        // gate / mix -> m_t
        float g  = sigmoidf_fast(zp);
        float hn = dA + dBp;
        float m  = fmaf(g, hn - hpl, hpl);
        // publish state (LDS + fire-and-forget global)
        if (q == 0) {
            hbuf[parOut][((r >> 5) * 36) + (r & 31)] = m;
            Hb[(size_t)t * NS + r] = m;
        }
        // wave stats of m_t
        float s  = wave_sum63(m);
        float s2 = wave_sum63(m * m);
        if (lane == 63) { red[parOut][wave] = s; red[parOut][8 + wave] = s2; }
        if (tid == 0) musb[t - 1] = make_float2(mu, rstd);
        mp = m;
        if (t + 1 < NT) xdots(t + 1);
        bar_lds();
    };

    // boundary every 32 steps (after t = 30 mod 32): stage chunk s+2,
    // counted vmcnt so only the just-issued stage may remain outstanding.
    auto boundary = [&](int t) {
        const int s2 = (t >> 5) + 2;
        if (s2 < NT / 32)
            stage16(xstage + (size_t)s2 * 2048, &xlds[s2 & 1][wave * 4][0]);
        asm volatile("s_waitcnt vmcnt(1)" ::: "memory");
        __builtin_amdgcn_s_barrier();
        asm volatile("" ::: "memory");
    };

    for (int t = 1; t + 1 < NT; t += 2) {
        body(t, 0, 1);
        body(t + 1, 1, 0);
        if (((t + 1) & 31) == 30) boundary(t + 1);
    }
    body(NT - 1, 0, 1);

    // epilogue: stats of m_{NT-1}
    {
        const f4* rp = (const f4*)&red[1][0];
        f4 sa = rp[0], sb = rp[1], sc = rp[2], sd = rp[3];
        float S  = ((sa.x + sa.y) + (sa.z + sa.w)) + ((sb.x + sb.y) + (sb.z + sb.w));
        float S2 = ((sc.x + sc.y) + (sc.z + sc.w)) + ((sd.x + sd.y) + (sd.z + sd.w));
        float mu   = S * (1.0f / 512.0f);
        float var  = fmaf(S2, 1.0f / 512.0f, -mu * mu);
        float rstd = 1.0f / sqrtf(var + 1e-5f);
        if (tid == 0) musb[NT - 1] = make_float2(mu, rstd);
    }
}

// =====================================================================
// K2: y + statistics. grid = NB x 32 chunks of 64 t, 512 threads.
// Thread: o = tid&63, kh = (tid>>6)&1 (K-half), tg = tid>>7 (t-group).
// Weights pinned. Phase 1: y-partials to LDS. Phase 2: reductions.
// =====================================================================
#define CHUNKS 32
#define TCH (NT / CHUNKS)   // 64

__global__ __launch_bounds__(512, 2) void y_stats_kernel(
    const float* __restrict__ H,
    const float* __restrict__ x,
    const float* __restrict__ Cm,
    const float* __restrict__ Dm,
    const float* __restrict__ gamma,
    const float* __restrict__ beta,
    const float* __restrict__ musig,
    float* __restrict__ SY,
    float* __restrict__ SYY,
    float* __restrict__ meanx,     // raw sums (divided in K3)
    float* __restrict__ nsum,
    float* __restrict__ dsum,
    float* __restrict__ outFinal)
{
    const int b     = blockIdx.x >> 5;
    const int chunk = blockIdx.x & 31;
    const int tid   = threadIdx.x;
    const int o     = tid & 63;
    const int sub   = tid >> 6;      // 0..7
    const int kh    = sub & 1;
    const int tg    = sub >> 1;      // 0..3
    const int lane  = tid & 63;

    __shared__ float pbuf[TCH + 1][2 * NO];   // 33.3 KB
    __shared__ float nd[2];

    // ---- C half (gamma folded) + D half, named f4s, pinned ----
    f4 C0,C1,C2,C3,C4,C5,C6,C7,C8,C9,C10,C11,C12,C13,C14,C15;
    float sCg = 0.f, cB = 0.f;
    {
        const f4* cp = (const f4*)(Cm + (size_t)o * NS + kh * 64);
        const f4* gp = (const f4*)(gamma + kh * 64);
        const f4* bp = (const f4*)(beta  + kh * 64);
        f4 v, g, be;
#define LOADC(J, CW) \
        v = cp[J]; g = gp[J]; be = bp[J]; \
        CW.x = v.x * g.x; CW.y = v.y * g.y; CW.z = v.z * g.z; CW.w = v.w * g.w; \
        sCg += (CW.x + CW.y) + (CW.z + CW.w); \
        cB = fmaf(v.x, be.x, cB); cB = fmaf(v.y, be.y, cB); \
        cB = fmaf(v.z, be.z, cB); cB = fmaf(v.w, be.w, cB);
        LOADC(0,C0) LOADC(1,C1) LOADC(2,C2) LOADC(3,C3)
        LOADC(4,C4) LOADC(5,C5) LOADC(6,C6) LOADC(7,C7)
        LOADC(8,C8) LOADC(9,C9) LOADC(10,C10) LOADC(11,C11)
        LOADC(12,C12) LOADC(13,C13) LOADC(14,C14) LOADC(15,C15)
#undef LOADC
    }
    f4 D0,D1,D2,D3,D4,D5,D6,D7;
    {
        const f4* dp = (const f4*)(Dm + (size_t)o * NI + kh * 32);
        D0 = dp[0]; D1 = dp[1]; D2 = dp[2]; D3 = dp[3];
        D4 = dp[4]; D5 = dp[5]; D6 = dp[6]; D7 = dp[7];
    }
    PIN4(C0); PIN4(C1); PIN4(C2); PIN4(C3); PIN4(C4); PIN4(C5); PIN4(C6); PIN4(C7);
    PIN4(C8); PIN4(C9); PIN4(C10); PIN4(C11); PIN4(C12); PIN4(C13); PIN4(C14); PIN4(C15);
    PIN4(D0); PIN4(D1); PIN4(D2); PIN4(D3); PIN4(D4); PIN4(D5); PIN4(D6); PIN4(D7);
    asm("" : "+v"(sCg), "+v"(cB));

    const float*  Hb  = H + ((size_t)b * NT) * NS;
    const float*  xb  = x + ((size_t)b * NT) * NI;
    const float2* msb = (const float2*)musig + (size_t)b * NT;
    const int t0 = chunk * TCH;

    if (tid < 2) nd[tid] = 0.f;

    // meanx partials: 4 waves x 16 t each, column o
    if (sub < 4) {
        float s = 0.f;
        const float* xk = xb + o;
        #pragma unroll 4
        for (int i = 0; i < 16; ++i) s += xk[(size_t)(t0 + sub * 16 + i) * NI];
        atomicAdd(&meanx[b * NI + o], s);
    }

    // ---- phase 1: y-partials into LDS (tg==0 also does the t0-1 halo) ----
    {
        const int i_start = (tg == 0 && t0 > 0) ? -1 : 0;
        for (int i = i_start; i < 16; ++i) {
            const int t = t0 + tg * 16 + i;
            float2 ms = msb[t];
            const f4* hp = (const f4*)(Hb + (size_t)t * NS + kh * 64);
            const f4* xp = (const f4*)(xb + (size_t)t * NI + kh * 32);
            float y0 = 0.f, y1 = 0.f, y2 = 0.f, y3 = 0.f;
            f4 hv;
            hv = hp[0];  FMA4(y0,y1,y2,y3,C0,hv);
            hv = hp[1];  FMA4(y0,y1,y2,y3,C1,hv);
            hv = hp[2];  FMA4(y0,y1,y2,y3,C2,hv);
            hv = hp[3];  FMA4(y0,y1,y2,y3,C3,hv);
            hv = hp[4];  FMA4(y0,y1,y2,y3,C4,hv);
            hv = hp[5];  FMA4(y0,y1,y2,y3,C5,hv);
            hv = hp[6];  FMA4(y0,y1,y2,y3,C6,hv);
            hv = hp[7];  FMA4(y0,y1,y2,y3,C7,hv);
            hv = hp[8];  FMA4(y0,y1,y2,y3,C8,hv);
            hv = hp[9];  FMA4(y0,y1,y2,y3,C9,hv);
            hv = hp[10]; FMA4(y0,y1,y2,y3,C10,hv);
            hv = hp[11]; FMA4(y0,y1,y2,y3,C11,hv);
            hv = hp[12]; FMA4(y0,y1,y2,y3,C12,hv);
            hv = hp[13]; FMA4(y0,y1,y2,y3,C13,hv);
            hv = hp[14]; FMA4(y0,y1,y2,y3,C14,hv);
            hv = hp[15]; FMA4(y0,y1,y2,y3,C15,hv);
            float hdot = (y0 + y1) + (y2 + y3);
            float x0 = 0.f, x1 = 0.f, x2 = 0.f, x3 = 0.f;
            hv = xp[0];  FMA4(x0,x1,x2,x3,D0,hv);
            hv = xp[1];  FMA4(x0,x1,x2,x3,D1,hv);
            hv = xp[2];  FMA4(x0,x1,x2,x3,D2,hv);
            hv = xp[3];  FMA4(x0,x1,x2,x3,D3,hv);
            hv = xp[4];  FMA4(x0,x1,x2,x3,D4,hv);
            hv = xp[5];  FMA4(x0,x1,x2,x3,D5,hv);
            hv = xp[6];  FMA4(x0,x1,x2,x3,D6,hv);
            hv = xp[7];  FMA4(x0,x1,x2,x3,D7,hv);
            float xdot = (x0 + x1) + (x2 + x3);
            pbuf[tg * 16 + i + 1][kh * 64 + o] =
                fmaf(ms.y, fmaf(-ms.x, sCg, hdot), cB + xdot);
        }
    }
    __syncthreads();

    // ---- phase 2: wave sub reduces t = t0 + sub*8 .. +8 ----
    {
        const int tt0 = sub * 8;
        float yprev = pbuf[tt0][o] + pbuf[tt0][64 + o];
        float sy = 0.f, syy = 0.f, na = 0.f, da = 0.f;
        #pragma unroll
        for (int ii = 0; ii < 8; ++ii) {
            const int row = tt0 + ii + 1;
            float y = pbuf[row][o] + pbuf[row][64 + o];
            sy  += y;
            syy += y * y;
            float n2 = wave_sum63(y * y);
            na += sqrtf(n2);
            if (t0 + tt0 + ii > 0) {
                float df = y - yprev;
                float d2 = wave_sum63(df * df);
                da += sqrtf(d2);
            }
            yprev = y;
            if (chunk == 31 && sub == 7 && ii == 7)
                outFinal[b * NO + o] = y;
        }
        atomicAdd(&SY[b * NO + o], sy);
        atomicAdd(&SYY[b * NO + o], syy);
        if (lane == 63) {
            atomicAdd(&nd[0], na);
            atomicAdd(&nd[1], da);
        }
    }
    __syncthreads();
    if (tid == 0) { atomicAdd(nsum, nd[0]); atomicAdd(dsum, nd[1]); }
}

// =====================================================================
// K3: finalize scalars
// =====================================================================
__global__ __launch_bounds__(256) void finalize_kernel(
    const float* __restrict__ Wsel,
    const float* __restrict__ bsel,
    const float* __restrict__ meanx,   // raw sums
    const float* __restrict__ SY,
    const float* __restrict__ SYY,
    const float* __restrict__ nsum,
    const float* __restrict__ dsum,
    float* __restrict__ out)
{
    const int tid  = threadIdx.x;
    const int wave = tid >> 6;
    const int lane = tid & 63;
    __shared__ float rs[8];

    float accsel = 0.f;
    for (int idx = tid; idx < NB * NS; idx += 256) {
        int bb = idx >> 7;
        int s  = idx & 127;
        const float* mp = meanx + bb * NI;
        const float* wp = Wsel  + (size_t)s * NI;
        float dot = 0.f;
        #pragma unroll 8
        for (int k = 0; k < NI; ++k) dot = fmaf(mp[k], wp[k], dot);
        float z = fmaf(dot, 1.0f / NT, bsel[s]);
        accsel += 1.0f / (1.0f + expf(-z));
    }
    float accss = 0.f;
    for (int idx = tid; idx < NB * NO; idx += 256) {
        float s1 = SY[idx], s2 = SYY[idx];
        float var = (s2 - s1 * s1 * (1.0f / NT)) * (1.0f / (NT - 1));
        accss += sqrtf(fmaxf(var, 0.0f));
    }
    #pragma unroll
    for (int d = 1; d < 64; d <<= 1) {
        accsel += __shfl_xor(accsel, d);
        accss  += __shfl_xor(accss, d);
    }
    if (lane == 0) { rs[wave] = accsel; rs[4 + wave] = accss; }
    __syncthreads();
    if (tid == 0) {
        float sel = (rs[0] + rs[1] + rs[2] + rs[3]) / (float)(NB * NS);
        float ss  = (rs[4] + rs[5] + rs[6] + rs[7]) / (float)(NB * NO);
        float tc  = 1.0f / (1.0f + dsum[0] / (float)(NB * (NT - 1)));
        float sm  = nsum[0] / (float)(NB * NT);
        out[4096] = tc;
        out[4097] = sm;
        out[4098] = sel;
        out[4099] = ss;
    }
}

extern "C" void kernel_launch(void* const* d_in, const int* in_sizes, int n_in,
                              void* d_out, int out_size, void* d_ws, size_t ws_size,
                              hipStream_t stream)
{
    (void)in_sizes; (void)n_in; (void)out_size; (void)ws_size;
    const float* x     = (const float*)d_in[0];
    const float* A     = (const float*)d_in[1];
    const float* Bm    = (const float*)d_in[2];
    const float* Cm    = (const float*)d_in[3];
    const float* Dm    = (const float*)d_in[4];
    const float* Wsel  = (const float*)d_in[5];
    const float* bsel  = (const float*)d_in[6];
    const float* gamma = (const float*)d_in[7];
    const float* beta  = (const float*)d_in[8];
    float* out = (float*)d_out;

    char* ws = (char*)d_ws;
    size_t off = 0;
    float* H     = (float*)(ws + off); off += (size_t)NB * NT * NS * sizeof(float); // 64 MB
    float* musig = (float*)(ws + off); off += (size_t)NB * NT * 2 * sizeof(float);  // 1 MB
    char*  zbase = ws + off;
    float* SY    = (float*)(ws + off); off += NB * NO * sizeof(float);
    float* SYY   = (float*)(ws + off); off += NB * NO * sizeof(float);
    float* meanx = (float*)(ws + off); off += NB * NI * sizeof(float);
    float* nsum  = (float*)(ws + off); off += sizeof(float);
    float* dsum  = (float*)(ws + off); off += sizeof(float);
    size_t zbytes = (size_t)((char*)(dsum + 1) - zbase);

    hipMemsetAsync(zbase, 0, zbytes, stream);
    scan_kernel<<<NB, 512, 0, stream>>>(x, A, Bm, Wsel, bsel, gamma, beta, H, musig);
    y_stats_kernel<<<NB * CHUNKS, 512, 0, stream>>>(H, x, Cm, Dm, gamma, beta, musig,
                                                    SY, SYY, meanx, nsum, dsum, out);
    finalize_kernel<<<1, 256, 0, stream>>>(Wsel, bsel, meanx, SY, SYY, nsum, dsum, out);
}

// Round 7
// 1681.073 us; speedup vs baseline: 1.6762x; 1.1557x over previous
//
#include <hip/hip_runtime.h>
#include <math.h>

#define NB 64
#define NT 2048
#define NI 64
#define NS 128
#define NO 64

typedef float4 f4;

#define PIN4(v) asm("" : "+v"((v).x), "+v"((v).y), "+v"((v).z), "+v"((v).w))
#define FMA4(a0,a1,a2,a3,W_,V_) \
    a0 = fmaf((W_).x, (V_).x, a0); a1 = fmaf((W_).y, (V_).y, a1); \
    a2 = fmaf((W_).z, (V_).z, a2); a3 = fmaf((W_).w, (V_).w, a3)

template<int CTRL>
__device__ __forceinline__ float dpp_add(float v) {
    int t = __builtin_amdgcn_update_dpp(0, __float_as_int(v), CTRL, 0xF, 0xF, true);
    return v + __int_as_float(t);
}
__device__ __forceinline__ float qxor1(float v) { return dpp_add<0xB1>(v); }
__device__ __forceinline__ float qxor2(float v) { return dpp_add<0x4E>(v); }
__device__ __forceinline__ float wave_sum63(float v) {
    v = dpp_add<0x111>(v); v = dpp_add<0x112>(v); v = dpp_add<0x114>(v);
    v = dpp_add<0x118>(v); v = dpp_add<0x142>(v); v = dpp_add<0x143>(v);
    return v;
}
__device__ __forceinline__ float sigmoidf_fast(float z) {
    float e = __builtin_amdgcn_exp2f(z * -1.442695041f);
    return __builtin_amdgcn_rcpf(1.0f + e);
}
__device__ __forceinline__ void bar_lds() {
    asm volatile("s_waitcnt lgkmcnt(0)" ::: "memory");
    __builtin_amdgcn_s_barrier();
    asm volatile("" ::: "memory");
}
__device__ __forceinline__ void stage16(const float* g, float* l) {
    __builtin_amdgcn_global_load_lds(
        (const __attribute__((address_space(1))) void*)g,
        (__attribute__((address_space(3))) void*)l, 16, 0, 0);
}

// =====================================================================
// K0: proj — precompute P[b][t][0..127]=Bm·x_t, [128..255]=Wsel·x_t+bsel
// grid = NB*32 blocks x 256 thr. Runs on all CUs, off the critical path.
// =====================================================================
__global__ __launch_bounds__(256, 2) void proj_kernel(
    const float* __restrict__ x,
    const float* __restrict__ Bm,
    const float* __restrict__ Wsel,
    const float* __restrict__ bsel,
    float* __restrict__ P)
{
    const int b   = blockIdx.x >> 5;
    const int c   = blockIdx.x & 31;        // 64-t chunk
    const int tid = threadIdx.x;            // 0..255 = output row j

    __shared__ __align__(16) float xs[64][64];   // 16 KB
    {
        const f4* src = (const f4*)(x + ((size_t)b * NT + c * 64) * NI);
        f4* dst = (f4*)&xs[0][0];
        #pragma unroll
        for (int k = 0; k < 4; ++k) dst[tid + k * 256] = src[tid + k * 256];
    }

    const float* wrow = (tid < 128) ? (Bm + (size_t)tid * NI)
                                    : (Wsel + (size_t)(tid - 128) * NI);
    const float bias = (tid < 128) ? 0.f : bsel[tid - 128];

    f4 W0,W1,W2,W3,W4,W5,W6,W7,W8,W9,W10,W11,W12,W13,W14,W15;
    {
        const f4* wp = (const f4*)wrow;
        W0=wp[0]; W1=wp[1]; W2=wp[2]; W3=wp[3]; W4=wp[4]; W5=wp[5]; W6=wp[6]; W7=wp[7];
        W8=wp[8]; W9=wp[9]; W10=wp[10]; W11=wp[11]; W12=wp[12]; W13=wp[13]; W14=wp[14]; W15=wp[15];
    }
    PIN4(W0); PIN4(W1); PIN4(W2); PIN4(W3); PIN4(W4); PIN4(W5); PIN4(W6); PIN4(W7);
    PIN4(W8); PIN4(W9); PIN4(W10); PIN4(W11); PIN4(W12); PIN4(W13); PIN4(W14); PIN4(W15);

    __syncthreads();

    float* pout = P + ((size_t)b * NT + c * 64) * 256 + tid;
    for (int t = 0; t < 64; ++t) {
        const f4* xr = (const f4*)&xs[t][0];
        float a0 = bias, a1 = 0.f, a2 = 0.f, a3 = 0.f;
        f4 v;
        v = xr[0];  FMA4(a0,a1,a2,a3,W0,v);
        v = xr[1];  FMA4(a0,a1,a2,a3,W1,v);
        v = xr[2];  FMA4(a0,a1,a2,a3,W2,v);
        v = xr[3];  FMA4(a0,a1,a2,a3,W3,v);
        v = xr[4];  FMA4(a0,a1,a2,a3,W4,v);
        v = xr[5];  FMA4(a0,a1,a2,a3,W5,v);
        v = xr[6];  FMA4(a0,a1,a2,a3,W6,v);
        v = xr[7];  FMA4(a0,a1,a2,a3,W7,v);
        v = xr[8];  FMA4(a0,a1,a2,a3,W8,v);
        v = xr[9];  FMA4(a0,a1,a2,a3,W9,v);
        v = xr[10]; FMA4(a0,a1,a2,a3,W10,v);
        v = xr[11]; FMA4(a0,a1,a2,a3,W11,v);
        v = xr[12]; FMA4(a0,a1,a2,a3,W12,v);
        v = xr[13]; FMA4(a0,a1,a2,a3,W13,v);
        v = xr[14]; FMA4(a0,a1,a2,a3,W14,v);
        v = xr[15]; FMA4(a0,a1,a2,a3,W15,v);
        pout[(size_t)t * 256] = (a0 + a1) + (a2 + a3);
    }
}

// =====================================================================
// K1: sequential scan, templated on USEP.
//  USEP=1: reads precomputed dB/z from P (staged via global_load_lds).
//  USEP=0: round-6 proven path (inline x-projections).
// =====================================================================
template<int USEP>
__global__ __launch_bounds__(512, 2) void scan_kernel(
    const float* __restrict__ x,
    const float* __restrict__ P,
    const float* __restrict__ A,
    const float* __restrict__ Bm,
    const float* __restrict__ Wsel,
    const float* __restrict__ bsel,
    const float* __restrict__ gamma,
    const float* __restrict__ beta,
    float* __restrict__ H,
    float* __restrict__ musig)
{
    const int b    = blockIdx.x;
    const int tid  = threadIdx.x;
    const int q    = tid & 3;
    const int r    = tid >> 2;      // 0..127
    const int lane = tid & 63;
    const int wave = tid >> 6;      // 0..7

    __shared__ __align__(16) float hbuf[2][148];
    __shared__ __align__(16) float red[2][16];
    __shared__ __align__(16) float plds[2][32][USEP ? 256 : 64];

    // ---- A gamma-folded, pinned ----
    f4 Aw0, Aw1, Aw2, Aw3, Aw4, Aw5, Aw6, Aw7;
    float sAg = 0.f, aB = 0.f;
    {
        const f4* ga = (const f4*)(gamma + q * 32);
        const f4* bb = (const f4*)(beta  + q * 32);
        const f4* Ap = (const f4*)(A + (size_t)r * NS + q * 32);
        f4 g, be_, v;
#define LOADA(J, AW) \
        g = ga[J]; be_ = bb[J]; v = Ap[J]; \
        AW.x = v.x * g.x; AW.y = v.y * g.y; AW.z = v.z * g.z; AW.w = v.w * g.w; \
        sAg += (AW.x + AW.y) + (AW.z + AW.w); \
        aB = fmaf(v.x, be_.x, aB); aB = fmaf(v.y, be_.y, aB); \
        aB = fmaf(v.z, be_.z, aB); aB = fmaf(v.w, be_.w, aB);
        LOADA(0, Aw0) LOADA(1, Aw1) LOADA(2, Aw2) LOADA(3, Aw3)
        LOADA(4, Aw4) LOADA(5, Aw5) LOADA(6, Aw6) LOADA(7, Aw7)
#undef LOADA
        sAg = qxor2(qxor1(sAg));
        aB  = qxor2(qxor1(aB));
    }
    PIN4(Aw0); PIN4(Aw1); PIN4(Aw2); PIN4(Aw3);
    PIN4(Aw4); PIN4(Aw5); PIN4(Aw6); PIN4(Aw7);

    f4 Bw0, Bw1, Bw2, Bw3, Ww0, Ww1, Ww2, Ww3;
    float bs = 0.f;
    if constexpr (!USEP) {
        const f4* Bp = (const f4*)(Bm   + (size_t)r * NI + q * 16);
        const f4* Wp = (const f4*)(Wsel + (size_t)r * NI + q * 16);
        Bw0 = Bp[0]; Bw1 = Bp[1]; Bw2 = Bp[2]; Bw3 = Bp[3];
        Ww0 = Wp[0]; Ww1 = Wp[1]; Ww2 = Wp[2]; Ww3 = Wp[3];
        bs = bsel[r];
        PIN4(Bw0); PIN4(Bw1); PIN4(Bw2); PIN4(Bw3);
        PIN4(Ww0); PIN4(Ww1); PIN4(Ww2); PIN4(Ww3);
        asm("" : "+v"(bs));
    }
    float gm = gamma[r], bt = beta[r];
    asm("" : "+v"(sAg), "+v"(aB), "+v"(gm), "+v"(bt));

    // ---- stage chunks 0,1 ----
    const float* xstage = x + (size_t)b * NT * NI + wave * 256 + lane * 4;
    const float* pstage = P + (size_t)b * NT * 256 + wave * 256 + lane * 4;
    if constexpr (USEP) {
        #pragma unroll
        for (int c = 0; c < 2; ++c)
            #pragma unroll
            for (int k = 0; k < 4; ++k)
                stage16(pstage + (size_t)(c * 32 + k * 8) * 256,
                        &plds[c][k * 8 + wave][0]);
    } else {
        stage16(xstage,        &plds[0][wave * 4][0]);
        stage16(xstage + 2048, &plds[1][wave * 4][0]);
    }
    asm volatile("s_waitcnt vmcnt(0)" ::: "memory");
    __syncthreads();

    float zp = 0.f, dBp = 0.f;     // X path pending
    float pbp = 0.f, pzp = 0.f;    // P path pending
    auto xdots = [&](int t) {
        const f4* xp = (const f4*)&plds[(t >> 5) & 1][t & 31][q * 16];
        f4 v0 = xp[0], v1 = xp[1], v2 = xp[2], v3 = xp[3];
        float p0 = 0.f, p1 = 0.f, p2 = 0.f, p3 = 0.f;
        float w0 = 0.f, w1 = 0.f, w2 = 0.f, w3 = 0.f;
        FMA4(p0, p1, p2, p3, Bw0, v0); FMA4(p0, p1, p2, p3, Bw1, v1);
        FMA4(p0, p1, p2, p3, Bw2, v2); FMA4(p0, p1, p2, p3, Bw3, v3);
        FMA4(w0, w1, w2, w3, Ww0, v0); FMA4(w0, w1, w2, w3, Ww1, v1);
        FMA4(w0, w1, w2, w3, Ww2, v2); FMA4(w0, w1, w2, w3, Ww3, v3);
        dBp = qxor2(qxor1((p0 + p1) + (p2 + p3)));
        zp  = qxor2(qxor1((w0 + w1) + (w2 + w3))) + bs;
    };
    auto pread = [&](int t) {
        const float* pl = &plds[(t >> 5) & 1][t & 31][0];
        pbp = pl[r]; pzp = pl[128 + r];
    };

    float*  Hb   = H + ((size_t)b * NT) * NS;
    float2* musb = (float2*)musig + (size_t)b * NT;

    // ---- peel t = 0 ----
    float mp;
    if constexpr (USEP) pread(0); else xdots(0);
    {
        float g = sigmoidf_fast(USEP ? pzp : zp);
        mp = g * (USEP ? pbp : dBp);
        if (q == 0) {
            hbuf[0][((r >> 5) * 36) + (r & 31)] = mp;
            Hb[r] = mp;
        }
        float s  = wave_sum63(mp);
        float s2 = wave_sum63(mp * mp);
        if (lane == 63) { red[0][wave] = s; red[0][8 + wave] = s2; }
    }
    if constexpr (USEP) pread(1); else xdots(1);
    bar_lds();

    auto body = [&](int t, int parIn, int parOut) {
        const f4* rp = (const f4*)&red[parIn][0];
        f4 sa = rp[0], sb = rp[1], sc = rp[2], sd = rp[3];
        float S  = ((sa.x + sa.y) + (sa.z + sa.w)) + ((sb.x + sb.y) + (sb.z + sb.w));
        float S2 = ((sc.x + sc.y) + (sc.z + sc.w)) + ((sd.x + sd.y) + (sd.z + sd.w));
        float mu   = S * (1.0f / 512.0f);
        float var  = fmaf(S2, 1.0f / 512.0f, -mu * mu);
        float rstd = 1.0f / sqrtf(var + 1e-5f);
        const f4* hp = (const f4*)&hbuf[parIn][q * 36];
        f4 h0 = hp[0], h1 = hp[1], h2 = hp[2], h3 = hp[3];
        f4 h4 = hp[4], h5 = hp[5], h6 = hp[6], h7 = hp[7];
        float d0 = 0.f, d1 = 0.f, d2 = 0.f, d3 = 0.f;
        FMA4(d0, d1, d2, d3, Aw0, h0); FMA4(d0, d1, d2, d3, Aw1, h1);
        FMA4(d0, d1, d2, d3, Aw2, h2); FMA4(d0, d1, d2, d3, Aw3, h3);
        FMA4(d0, d1, d2, d3, Aw4, h4); FMA4(d0, d1, d2, d3, Aw5, h5);
        FMA4(d0, d1, d2, d3, Aw6, h6); FMA4(d0, d1, d2, d3, Aw7, h7);
        float dAm = qxor2(qxor1((d0 + d1) + (d2 + d3)));
        float dA  = fmaf(rstd, fmaf(-mu, sAg, dAm), aB);
        float hpl = fmaf((mp - mu) * rstd, gm, bt);
        float g   = sigmoidf_fast(USEP ? pzp : zp);
        float hn  = dA + (USEP ? pbp : dBp);
        float m   = fmaf(g, hn - hpl, hpl);
        if (q == 0) {
            hbuf[parOut][((r >> 5) * 36) + (r & 31)] = m;
            Hb[(size_t)t * NS + r] = m;
        }
        float s  = wave_sum63(m);
        float s2 = wave_sum63(m * m);
        if (lane == 63) { red[parOut][wave] = s; red[parOut][8 + wave] = s2; }
        if (tid == 0) musb[t - 1] = make_float2(mu, rstd);
        mp = m;
        if (t + 1 < NT) { if constexpr (USEP) pread(t + 1); else xdots(t + 1); }
        bar_lds();
    };

    // boundary after the pair ending at t+1 = 32s+30: all chunk-s reads done
    // (t=32s+31 values already prefetched into regs). Stage s+2; counted
    // vmcnt so only just-issued stages may remain; barrier republishes.
    auto boundary = [&](int t) {
        const int s2 = (t >> 5) + 2;
        if constexpr (USEP) {
            if (s2 < NT / 32) {
                #pragma unroll
                for (int k = 0; k < 4; ++k)
                    stage16(pstage + (size_t)(s2 * 32 + k * 8) * 256,
                            &plds[s2 & 1][k * 8 + wave][0]);
            }
            asm volatile("s_waitcnt vmcnt(4)" ::: "memory");
        } else {
            if (s2 < NT / 32)
                stage16(xstage + (size_t)s2 * 2048, &plds[s2 & 1][wave * 4][0]);
            asm volatile("s_waitcnt vmcnt(1)" ::: "memory");
        }
        __builtin_amdgcn_s_barrier();
        asm volatile("" ::: "memory");
    };

    for (int t = 1; t + 1 < NT; t += 2) {
        body(t, 0, 1);
        body(t + 1, 1, 0);
        if (((t + 1) & 31) == 30) boundary(t + 1);
    }
    body(NT - 1, 0, 1);

    {
        const f4* rp = (const f4*)&red[1][0];
        f4 sa = rp[0], sb = rp[1], sc = rp[2], sd = rp[3];
        float S  = ((sa.x + sa.y) + (sa.z + sa.w)) + ((sb.x + sb.y) + (sb.z + sb.w));
        float S2 = ((sc.x + sc.y) + (sc.z + sc.w)) + ((sd.x + sd.y) + (sd.z + sd.w));
        float mu   = S * (1.0f / 512.0f);
        float var  = fmaf(S2, 1.0f / 512.0f, -mu * mu);
        float rstd = 1.0f / sqrtf(var + 1e-5f);
        if (tid == 0) musb[NT - 1] = make_float2(mu, rstd);
    }
}

// =====================================================================
// K2: y + statistics, register-blocked: each thread computes 2 outputs
// (o2, o2+32) over a K-quarter kq; loads are half-wave-uniform.
// kq low bit combined via shfl_xor(32), high bit via pbuf as before.
// =====================================================================
#define CHUNKS 32
#define TCH (NT / CHUNKS)   // 64

__global__ __launch_bounds__(512, 1) void y_stats_kernel(
    const float* __restrict__ H,
    const float* __restrict__ x,
    const float* __restrict__ Cm,
    const float* __restrict__ Dm,
    const float* __restrict__ gamma,
    const float* __restrict__ beta,
    const float* __restrict__ musig,
    float* __restrict__ SY,
    float* __restrict__ SYY,
    float* __restrict__ meanx,
    float* __restrict__ nsum,
    float* __restrict__ dsum,
    float* __restrict__ outFinal)
{
    const int b     = blockIdx.x >> 5;
    const int chunk = blockIdx.x & 31;
    const int tid   = threadIdx.x;
    const int o2    = tid & 31;          // outputs o2, o2+32
    const int kq    = (tid >> 5) & 3;    // K-quarter
    const int tg    = tid >> 7;          // 0..3, 16 t each
    const int lane  = tid & 63;
    const int sub   = tid >> 6;          // wave id 0..7
    const int o     = tid & 63;          // phase-2 output col

    __shared__ float pbuf[TCH + 1][2 * NO];   // 33.3 KB
    __shared__ float nd[2];

    // C quarters for both outputs (gamma folded) + per-quarter fold scalars
    f4 CA0,CA1,CA2,CA3,CA4,CA5,CA6,CA7, CB0,CB1,CB2,CB3,CB4,CB5,CB6,CB7;
    float sCgA = 0.f, cBA = 0.f, sCgB = 0.f, cBB = 0.f;
    {
        const f4* cpA = (const f4*)(Cm + (size_t)o2 * NS + kq * 32);
        const f4* cpB = (const f4*)(Cm + (size_t)(o2 + 32) * NS + kq * 32);
        const f4* gp  = (const f4*)(gamma + kq * 32);
        const f4* bp  = (const f4*)(beta  + kq * 32);
        f4 vv, gg, bb;
#define LC(J, CW, CP, SG, CBs) \
        vv = CP[J]; gg = gp[J]; bb = bp[J]; \
        CW.x = vv.x * gg.x; CW.y = vv.y * gg.y; CW.z = vv.z * gg.z; CW.w = vv.w * gg.w; \
        SG += (CW.x + CW.y) + (CW.z + CW.w); \
        CBs = fmaf(vv.x, bb.x, CBs); CBs = fmaf(vv.y, bb.y, CBs); \
        CBs = fmaf(vv.z, bb.z, CBs); CBs = fmaf(vv.w, bb.w, CBs);
        LC(0,CA0,cpA,sCgA,cBA) LC(1,CA1,cpA,sCgA,cBA) LC(2,CA2,cpA,sCgA,cBA) LC(3,CA3,cpA,sCgA,cBA)
        LC(4,CA4,cpA,sCgA,cBA) LC(5,CA5,cpA,sCgA,cBA) LC(6,CA6,cpA,sCgA,cBA) LC(7,CA7,cpA,sCgA,cBA)
        LC(0,CB0,cpB,sCgB,cBB) LC(1,CB1,cpB,sCgB,cBB) LC(2,CB2,cpB,sCgB,cBB) LC(3,CB3,cpB,sCgB,cBB)
        LC(4,CB4,cpB,sCgB,cBB) LC(5,CB5,cpB,sCgB,cBB) LC(6,CB6,cpB,sCgB,cBB) LC(7,CB7,cpB,sCgB,cBB)
#undef LC
    }
    f4 DA0,DA1,DA2,DA3, DB0,DB1,DB2,DB3;
    {
        const f4* dpA = (const f4*)(Dm + (size_t)o2 * NI + kq * 16);
        const f4* dpB = (const f4*)(Dm + (size_t)(o2 + 32) * NI + kq * 16);
        DA0 = dpA[0]; DA1 = dpA[1]; DA2 = dpA[2]; DA3 = dpA[3];
        DB0 = dpB[0]; DB1 = dpB[1]; DB2 = dpB[2]; DB3 = dpB[3];
    }
    PIN4(CA0); PIN4(CA1); PIN4(CA2); PIN4(CA3); PIN4(CA4); PIN4(CA5); PIN4(CA6); PIN4(CA7);
    PIN4(CB0); PIN4(CB1); PIN4(CB2); PIN4(CB3); PIN4(CB4); PIN4(CB5); PIN4(CB6); PIN4(CB7);
    PIN4(DA0); PIN4(DA1); PIN4(DA2); PIN4(DA3); PIN4(DB0); PIN4(DB1); PIN4(DB2); PIN4(DB3);
    asm("" : "+v"(sCgA), "+v"(cBA), "+v"(sCgB), "+v"(cBB));

    const float*  Hb  = H + ((size_t)b * NT) * NS;
    const float*  xb  = x + ((size_t)b * NT) * NI;
    const float2* msb = (const float2*)musig + (size_t)b * NT;
    const int t0 = chunk * TCH;

    if (tid < 2) nd[tid] = 0.f;

    // meanx partials: waves 0-3, 16 t each, column o
    if (sub < 4) {
        float s = 0.f;
        const float* xk = xb + o;
        #pragma unroll 4
        for (int i = 0; i < 16; ++i) s += xk[(size_t)(t0 + sub * 16 + i) * NI];
        atomicAdd(&meanx[b * NI + o], s);
    }

    // ---- phase 1 ----
    {
        const int khigh = sub & 1;
        const int i_start = (tg == 0 && t0 > 0) ? -1 : 0;
        for (int i = i_start; i < 16; ++i) {
            const int t = t0 + tg * 16 + i;
            float2 ms = msb[t];
            const f4* hp = (const f4*)(Hb + (size_t)t * NS + kq * 32);
            const f4* xp = (const f4*)(xb + (size_t)t * NI + kq * 16);
            float a0=0.f,a1=0.f,a2=0.f,a3=0.f, b0=0.f,b1=0.f,b2=0.f,b3=0.f;
            f4 hv;
            hv = hp[0]; FMA4(a0,a1,a2,a3,CA0,hv); FMA4(b0,b1,b2,b3,CB0,hv);
            hv = hp[1]; FMA4(a0,a1,a2,a3,CA1,hv); FMA4(b0,b1,b2,b3,CB1,hv);
            hv = hp[2]; FMA4(a0,a1,a2,a3,CA2,hv); FMA4(b0,b1,b2,b3,CB2,hv);
            hv = hp[3]; FMA4(a0,a1,a2,a3,CA3,hv); FMA4(b0,b1,b2,b3,CB3,hv);
            hv = hp[4]; FMA4(a0,a1,a2,a3,CA4,hv); FMA4(b0,b1,b2,b3,CB4,hv);
            hv = hp[5]; FMA4(a0,a1,a2,a3,CA5,hv); FMA4(b0,b1,b2,b3,CB5,hv);
            hv = hp[6]; FMA4(a0,a1,a2,a3,CA6,hv); FMA4(b0,b1,b2,b3,CB6,hv);
            hv = hp[7]; FMA4(a0,a1,a2,a3,CA7,hv); FMA4(b0,b1,b2,b3,CB7,hv);
            float hdotA = (a0 + a1) + (a2 + a3);
            float hdotB = (b0 + b1) + (b2 + b3);
            float xa0=0.f,xa1=0.f,xa2=0.f,xa3=0.f, xb0=0.f,xb1=0.f,xb2=0.f,xb3=0.f;
            hv = xp[0]; FMA4(xa0,xa1,xa2,xa3,DA0,hv); FMA4(xb0,xb1,xb2,xb3,DB0,hv);
            hv = xp[1]; FMA4(xa0,xa1,xa2,xa3,DA1,hv); FMA4(xb0,xb1,xb2,xb3,DB1,hv);
            hv = xp[2]; FMA4(xa0,xa1,xa2,xa3,DA2,hv); FMA4(xb0,xb1,xb2,xb3,DB2,hv);
            hv = xp[3]; FMA4(xa0,xa1,xa2,xa3,DA3,hv); FMA4(xb0,xb1,xb2,xb3,DB3,hv);
            float xdotA = (xa0 + xa1) + (xa2 + xa3);
            float xdotB = (xb0 + xb1) + (xb2 + xb3);
            float pa = fmaf(ms.y, fmaf(-ms.x, sCgA, hdotA), cBA + xdotA);
            float pb = fmaf(ms.y, fmaf(-ms.x, sCgB, hdotB), cBB + xdotB);
            pa += __shfl_xor(pa, 32);     // combine kq low-bit pair
            pb += __shfl_xor(pb, 32);
            const int row = tg * 16 + i + 1;
            const int col = khigh * 64 + o2 + ((lane >= 32) ? 32 : 0);
            pbuf[row][col] = (lane >= 32) ? pb : pa;
        }
    }
    __syncthreads();

    // ---- phase 2: wave sub reduces 8 t ----
    {
        const int tt0 = sub * 8;
        float yprev = pbuf[tt0][o] + pbuf[tt0][64 + o];
        float sy = 0.f, syy = 0.f, na = 0.f, da = 0.f;
        #pragma unroll
        for (int ii = 0; ii < 8; ++ii) {
            const int row = tt0 + ii + 1;
            float y = pbuf[row][o] + pbuf[row][64 + o];
            sy  += y;
            syy += y * y;
            float n2 = wave_sum63(y * y);
            na += sqrtf(n2);
            if (t0 + tt0 + ii > 0) {
                float df = y - yprev;
                float d2 = wave_sum63(df * df);
                da += sqrtf(d2);
            }
            yprev = y;
            if (chunk == 31 && sub == 7 && ii == 7)
                outFinal[b * NO + o] = y;
        }
        atomicAdd(&SY[b * NO + o], sy);
        atomicAdd(&SYY[b * NO + o], syy);
        if (lane == 63) {
            atomicAdd(&nd[0], na);
            atomicAdd(&nd[1], da);
        }
    }
    __syncthreads();
    if (tid == 0) { atomicAdd(nsum, nd[0]); atomicAdd(dsum, nd[1]); }
}

// =====================================================================
// K3: finalize scalars
// =====================================================================
__global__ __launch_bounds__(256) void finalize_kernel(
    const float* __restrict__ Wsel,
    const float* __restrict__ bsel,
    const float* __restrict__ meanx,
    const float* __restrict__ SY,
    const float* __restrict__ SYY,
    const float* __restrict__ nsum,
    const float* __restrict__ dsum,
    float* __restrict__ out)
{
    const int tid  = threadIdx.x;
    const int wave = tid >> 6;
    const int lane = tid & 63;
    __shared__ float rs[8];

    float accsel = 0.f;
    for (int idx = tid; idx < NB * NS; idx += 256) {
        int bb = idx >> 7;
        int s  = idx & 127;
        const float* mp = meanx + bb * NI;
        const float* wp = Wsel  + (size_t)s * NI;
        float dot = 0.f;
        #pragma unroll 8
        for (int k = 0; k < NI; ++k) dot = fmaf(mp[k], wp[k], dot);
        float z = fmaf(dot, 1.0f / NT, bsel[s]);
        accsel += 1.0f / (1.0f + expf(-z));
    }
    float accss = 0.f;
    for (int idx = tid; idx < NB * NO; idx += 256) {
        float s1 = SY[idx], s2 = SYY[idx];
        float var = (s2 - s1 * s1 * (1.0f / NT)) * (1.0f / (NT - 1));
        accss += sqrtf(fmaxf(var, 0.0f));
    }
    #pragma unroll
    for (int d = 1; d < 64; d <<= 1) {
        accsel += __shfl_xor(accsel, d);
        accss  += __shfl_xor(accss, d);
    }
    if (lane == 0) { rs[wave] = accsel; rs[4 + wave] = accss; }
    __syncthreads();
    if (tid == 0) {
        float sel = (rs[0] + rs[1] + rs[2] + rs[3]) / (float)(NB * NS);
        float ss  = (rs[4] + rs[5] + rs[6] + rs[7]) / (float)(NB * NO);
        float tc  = 1.0f / (1.0f + dsum[0] / (float)(NB * (NT - 1)));
        float sm  = nsum[0] / (float)(NB * NT);
        out[4096] = tc;
        out[4097] = sm;
        out[4098] = sel;
        out[4099] = ss;
    }
}

extern "C" void kernel_launch(void* const* d_in, const int* in_sizes, int n_in,
                              void* d_out, int out_size, void* d_ws, size_t ws_size,
                              hipStream_t stream)
{
    (void)in_sizes; (void)n_in; (void)out_size;
    const float* x     = (const float*)d_in[0];
    const float* A     = (const float*)d_in[1];
    const float* Bm    = (const float*)d_in[2];
    const float* Cm    = (const float*)d_in[3];
    const float* Dm    = (const float*)d_in[4];
    const float* Wsel  = (const float*)d_in[5];
    const float* bsel  = (const float*)d_in[6];
    const float* gamma = (const float*)d_in[7];
    const float* beta  = (const float*)d_in[8];
    float* out = (float*)d_out;

    char* ws = (char*)d_ws;
    // stats region first (zeroed), then H, musig, then P (optional).
    float* SY    = (float*)(ws + 0);
    float* SYY   = (float*)(ws + 16384);
    float* meanx = (float*)(ws + 32768);
    float* nsum  = (float*)(ws + 49152);
    float* dsum  = (float*)(ws + 49156);
    const size_t zbytes = 49160;

    const size_t offH  = 65536;
    float* H     = (float*)(ws + offH);
    const size_t offMu = offH + (size_t)NB * NT * NS * sizeof(float);   // +64 MB
    float* musig = (float*)(ws + offMu);
    const size_t offP  = offMu + (size_t)NB * NT * 2 * sizeof(float);   // +1 MB
    float* P     = (float*)(ws + offP);
    const size_t needP = offP + (size_t)NB * NT * 256 * sizeof(float);  // +134 MB

    const bool useP = (ws_size >= needP);

    hipMemsetAsync(ws, 0, zbytes, stream);
    if (useP) {
        proj_kernel<<<NB * 32, 256, 0, stream>>>(x, Bm, Wsel, bsel, P);
        scan_kernel<1><<<NB, 512, 0, stream>>>(x, P, A, Bm, Wsel, bsel,
                                               gamma, beta, H, musig);
    } else {
        scan_kernel<0><<<NB, 512, 0, stream>>>(x, (const float*)ws, A, Bm, Wsel,
                                               bsel, gamma, beta, H, musig);
    }
    y_stats_kernel<<<NB * CHUNKS, 512, 0, stream>>>(H, x, Cm, Dm, gamma, beta, musig,
                                                    SY, SYY, meanx, nsum, dsum, out);
    finalize_kernel<<<1, 256, 0, stream>>>(Wsel, bsel, meanx, SY, SYY, nsum, dsum, out);
}